// Round 2
// 908.689 us; speedup vs baseline: 1.0469x; 1.0469x over previous
//
#include <hip/hip_runtime.h>
#include <stdint.h>

// Problem constants
#define N_    128
#define L_    128
#define V_    8000
#define IN_   64
#define H_    13
#define G_    52      // 4*H
#define E_    2048
#define TWOH  26
#define TOTW  742808  // total float elements across all 31 float inputs

typedef unsigned int   u32;
typedef unsigned short u16;

__device__ __forceinline__ float bfu(u16 u){
    u32 x = ((u32)u) << 16; float f; __builtin_memcpy(&f, &x, 4); return f;
}
// clamps are exact at saturation (sig(30)=1-9e-14, tanh(15)=1-2e-13)
__device__ __forceinline__ float sigf(float x){
    x = fminf(fmaxf(x, -30.f), 30.f);
    return 1.0f / (1.0f + __expf(-x));
}
__device__ __forceinline__ float tanh_(float x){
    x = fminf(fmaxf(x, -15.f), 15.f);
    float e = __expf(2.0f * x); return 1.0f - 2.0f / (e + 1.0f);
}

// ---------------------------------------------------------------------------
// K-1: dtype detection. fp32 arrays: low u16 of each dword is random mantissa
// bits -> bf16-exponent field uniform -> "wild". Genuine bf16 weights are
// essentially never wild. flag: 1 = fp32, 0 = bf16.
// ---------------------------------------------------------------------------
__global__ __launch_bounds__(64) void k_detect(const u16* __restrict__ emb_u16,
                                               int* __restrict__ flag){
    const int lane = threadIdx.x;
    int wild = 0;
    for (int i = lane; i < 1024; i += 64){
        u16 u = emb_u16[i];
        int e = (u >> 7) & 0xFF;
        int tame = (u == 0) || (u == 0x8000) || (e >= 0x60 && e <= 0x88);
        wild += !tame;
    }
    #pragma unroll
    for (int o = 32; o; o >>= 1) wild += __shfl_down(wild, o, 64);
    if (lane == 0) *flag = (wild > 200) ? 1 : 0;
}

// ---------------------------------------------------------------------------
// K0: materialize all 31 float inputs as fp32 into contiguous ws region.
// ---------------------------------------------------------------------------
struct P31 { const void* p[31]; };

__global__ __launch_bounds__(256) void k_convert(P31 a, const int* __restrict__ flag,
                                                 float* __restrict__ cw){
    const int fp32 = *flag;
    const int i = blockIdx.x * 256 + threadIdx.x;
    if (i >= TOTW) return;
    const int offs[32] = {
        0, 512064, 515392, 516068, 516120, 519448, 520124, 520176, 520852,
        520878, 521554, 521580, 521996, 522012, 522524, 522556, 523388,
        523414, 523830, 523846, 524358, 524390, 525222, 525248, 525300,
        525976, 526028, 526080, 526756, 526808, 734808, TOTW };
    int seg = 0;
    while (i >= offs[seg + 1]) ++seg;
    const int k = i - offs[seg];
    cw[i] = fp32 ? ((const float*)a.p[seg])[k] : bfu(((const u16*)a.p[seg])[k]);
}

// ---------------------------------------------------------------------------
// K1: proj[dir][t][g] = sum_k emb[t,k] * Wih_dir[g,k]
// ---------------------------------------------------------------------------
__global__ __launch_bounds__(128) void k_proj(const float* __restrict__ emb,
                                              const float* __restrict__ WihF,
                                              const float* __restrict__ WihB,
                                              float* __restrict__ projF,
                                              float* __restrict__ projB){
    __shared__ float x[IN_];
    const int t = blockIdx.x;
    const int tid = threadIdx.x;
    if (tid < IN_) x[tid] = emb[t * IN_ + tid];
    __syncthreads();
    if (tid < 2 * G_){
        const int dir = tid / G_;
        const int g   = tid - dir * G_;
        const float* w = (dir ? WihB : WihF) + g * IN_;
        float acc = 0.f;
        #pragma unroll
        for (int i = 0; i < IN_; ++i) acc += x[i] * w[i];
        (dir ? projB : projF)[t * G_ + g] = acc;
    }
}

// ---------------------------------------------------------------------------
// K2: biLSTM encoder. 1 block/node; wave0 = fwd, wave1 = bwd. Lane g (<52)
// owns one gate; h broadcast via shfl; next proj row prefetched.
// ---------------------------------------------------------------------------
__global__ __launch_bounds__(128) void k_lstm(const int* __restrict__ toks_g,
        const float* __restrict__ projF, const float* __restrict__ projB,
        const float* __restrict__ WhhF, const float* __restrict__ bF,
        const float* __restrict__ WhhB, const float* __restrict__ bB,
        const float* __restrict__ Wp1, const float* __restrict__ bp1,
        const float* __restrict__ Wp2, const float* __restrict__ bp2,
        float* __restrict__ state_h, float* __restrict__ state_c){
    __shared__ int   toks[L_];
    __shared__ float hcat[TWOH];
    __shared__ float ccat[TWOH];
    const int n = blockIdx.x, tid = threadIdx.x;
    const int wave = tid >> 6, lane = tid & 63;
    if (tid < L_) toks[tid] = toks_g[n * L_ + tid];

    const float* proj = wave ? projB : projF;
    const float* Whh  = wave ? WhhB : WhhF;
    const float* bp   = wave ? bB   : bF;

    float wh[H_];
    #pragma unroll
    for (int j = 0; j < H_; ++j) wh[j] = 0.f;
    float bb = 0.f;
    if (lane < G_){
        bb = bp[lane];
        #pragma unroll
        for (int j = 0; j < H_; ++j) wh[j] = Whh[lane * H_ + j];
    }
    __syncthreads();

    float h = 0.f, c = 0.f;
    int tok0 = wave ? toks[L_ - 1] : toks[0];
    float gpre = (lane < G_) ? proj[tok0 * G_ + lane] : 0.f;

    for (int t = 0; t < L_; ++t){
        float gv = gpre + bb;
        if (t + 1 < L_){
            int tn = wave ? toks[L_ - 2 - t] : toks[t + 1];
            gpre = (lane < G_) ? proj[tn * G_ + lane] : 0.f;   // prefetch
        }
        #pragma unroll
        for (int j = 0; j < H_; ++j) gv += __shfl(h, j, 64) * wh[j];
        float iv = __shfl(gv, lane,      64);
        float fv = __shfl(gv, lane + 13, 64);
        float gg = __shfl(gv, lane + 26, 64);
        float ov = __shfl(gv, lane + 39, 64);
        c = sigf(fv) * c + sigf(iv) * tanh_(gg);
        h = sigf(ov) * tanh_(c);
    }

    if (lane < H_){ hcat[wave * H_ + lane] = h; ccat[wave * H_ + lane] = c; }
    __syncthreads();

    if (lane < TWOH){
        if (wave == 0){
            float a = bp1[lane];
            #pragma unroll
            for (int k = 0; k < TWOH; ++k) a += hcat[k] * Wp1[lane * TWOH + k];
            state_h[n * TWOH + lane] = a;
        } else {
            float a = bp2[lane];
            #pragma unroll
            for (int k = 0; k < TWOH; ++k) a += ccat[k] * Wp2[lane * TWOH + k];
            state_c[n * TWOH + lane] = a;
        }
    }
}

// ---------------------------------------------------------------------------
// K3: two-layer GCN + final linear; one block per path (0 = h, 1 = c).
// GATHER formulation: build a dst-sorted CSR in LDS once, then each
// (node, feature) thread sums its in-edges. No feature atomics, no
// stride-32 same-bank serialization (xw padded to 33 floats/row).
// ---------------------------------------------------------------------------
__global__ __launch_bounds__(256) void k_gcn(const int* __restrict__ eidx,
        const float* __restrict__ state_h, const float* __restrict__ state_c,
        const float* gh_W1, const float* gh_b1, const float* gh_W2, const float* gh_b2,
        const float* gh_Wf, const float* gh_bf,
        const float* gc_W1, const float* gc_b1, const float* gc_W2, const float* gc_b2,
        const float* gc_Wf, const float* gc_bf,
        float* __restrict__ sh, float* __restrict__ sc){
    __shared__ float xs[N_][33];     // node features (padded: stride 33 banks)
    __shared__ float xw[N_][33];     // x @ W, gather source (padded)
    __shared__ float dinv[N_];
    __shared__ int   ptr[N_ + 1];    // CSR row offsets (by dst)
    __shared__ int   cnt[N_];
    __shared__ int   scn[N_];        // scan buffer
    __shared__ int   srcs[E_];       // CSR column (src node) array
    const int tid = threadIdx.x;
    const int p = blockIdx.x;
    const float* xin = p ? state_c : state_h;
    const float* W1  = p ? gc_W1 : gh_W1;  const float* b1  = p ? gc_b1 : gh_b1;
    const float* W2  = p ? gc_W2 : gh_W2;  const float* b2  = p ? gc_b2 : gh_b2;
    const float* Wf  = p ? gc_Wf : gh_Wf;  const float* bfp = p ? gc_bf : gh_bf;
    float* outp = p ? sc : sh;

    for (int i = tid; i < N_ * TWOH; i += 256) xs[i / TWOH][i % TWOH] = xin[i];
    if (tid < N_) cnt[tid] = 0;
    __syncthreads();
    // in-degree histogram (dst side); 2048 small LDS atomics, cheap
    for (int e = tid; e < E_; e += 256) atomicAdd(&cnt[eidx[E_ + e]], 1);
    __syncthreads();
    if (tid < N_){
        dinv[tid] = rsqrtf((float)cnt[tid] + 1.0f);   // +1 self loop
        scn[tid]  = cnt[tid];
    }
    __syncthreads();
    // Hillis-Steele inclusive scan over 128 entries (7 rounds)
    for (int off = 1; off < N_; off <<= 1){
        int v = 0;
        if (tid < N_ && tid >= off) v = scn[tid - off];
        __syncthreads();
        if (tid < N_) scn[tid] += v;
        __syncthreads();
    }
    if (tid < N_){
        ptr[tid + 1] = scn[tid];
        if (tid == 0) ptr[0] = 0;
        cnt[tid] = 0;
    }
    __syncthreads();
    // scatter edges into CSR slots (atomic slot grab per dst; order irrelevant)
    for (int e = tid; e < E_; e += 256){
        int d = eidx[E_ + e];
        int pos = atomicAdd(&cnt[d], 1);
        srcs[ptr[d] + pos] = eidx[e];
    }
    __syncthreads();

    // ---- layer 1: 26 -> 16 ----
    for (int i = tid; i < N_ * 16; i += 256){
        int nn = i >> 4, f = i & 15;
        float a = 0.f;
        #pragma unroll
        for (int k = 0; k < TWOH; ++k) a += xs[nn][k] * W1[k * 16 + f];
        xw[nn][f] = a;
    }
    __syncthreads();
    for (int i = tid; i < N_ * 16; i += 256){
        int nn = i >> 4, f = i & 15;
        float dn = dinv[nn];
        float a = dn * dn * xw[nn][f];                // self loop
        const int e1 = ptr[nn + 1];
        for (int e = ptr[nn]; e < e1; ++e){
            int s = srcs[e];
            a += dn * dinv[s] * xw[s][f];
        }
        a += b1[f];
        xs[nn][f] = a > 0.f ? a : 0.01f * a;          // xs reads all done
    }
    __syncthreads();

    // ---- layer 2: 16 -> 32 ----
    for (int i = tid; i < N_ * 32; i += 256){
        int nn = i >> 5, f = i & 31;
        float a = 0.f;
        #pragma unroll
        for (int k = 0; k < 16; ++k) a += xs[nn][k] * W2[k * 32 + f];
        xw[nn][f] = a;
    }
    __syncthreads();
    for (int i = tid; i < N_ * 32; i += 256){
        int nn = i >> 5, f = i & 31;
        float dn = dinv[nn];
        float a = dn * dn * xw[nn][f];
        const int e1 = ptr[nn + 1];
        for (int e = ptr[nn]; e < e1; ++e){
            int s = srcs[e];
            a += dn * dinv[s] * xw[s][f];
        }
        a += b2[f];
        xs[nn][f] = a > 0.f ? a : 0.01f * a;
    }
    __syncthreads();

    // ---- final linear: 32 -> 26 ----
    for (int i = tid; i < N_ * TWOH; i += 256){
        int nn = i / TWOH, d = i % TWOH;
        float a = bfp[d];
        #pragma unroll
        for (int k = 0; k < 32; ++k) a += xs[nn][k] * Wf[k * TWOH + d];
        outp[i] = a;
    }
}

// ---------------------------------------------------------------------------
// K4: decoder rows. One thread per (n,l). l>0: h0=c0=0 (scalar gates only).
// ---------------------------------------------------------------------------
__global__ __launch_bounds__(256) void k_dec(const int* __restrict__ toks,
        const float* __restrict__ sh, const float* __restrict__ sc,
        const float* WihF, const float* WhhF, const float* bF,
        const float* WihB, const float* WhhB, const float* bB,
        float* __restrict__ dec){
    __shared__ float wih[2][G_], bias[2][G_], whh[2][G_][H_];
    const int tid = threadIdx.x;
    for (int i = tid; i < 2 * G_; i += 256){
        int d = i / G_, k = i % G_;
        wih[d][k]  = (d ? WihB : WihF)[k];
        bias[d][k] = (d ? bB : bF)[k];
    }
    for (int i = tid; i < 2 * G_ * H_; i += 256){
        int d = i / (G_ * H_), rr = i % (G_ * H_), k = rr / H_, j = rr % H_;
        whh[d][k][j] = (d ? WhhB : WhhF)[k * H_ + j];
    }
    __syncthreads();

    const int r = blockIdx.x * 256 + tid;
    const int n = r >> 7, l = r & 127;
    const bool first = (l == 0);
    const float prev = first ? -1.0f : (float)toks[n * L_ + l - 1];

    for (int d = 0; d < 2; ++d){
        float h0[H_], c0[H_];
        #pragma unroll
        for (int j = 0; j < H_; ++j){
            h0[j] = first ? sh[n * TWOH + d * H_ + j] : 0.f;
            c0[j] = first ? sc[n * TWOH + d * H_ + j] : 0.f;
        }
        #pragma unroll
        for (int j = 0; j < H_; ++j){
            float gi = prev * wih[d][j]      + bias[d][j];
            float gf = prev * wih[d][13 + j] + bias[d][13 + j];
            float gg = prev * wih[d][26 + j] + bias[d][26 + j];
            float go = prev * wih[d][39 + j] + bias[d][39 + j];
            if (first){
                #pragma unroll
                for (int k = 0; k < H_; ++k){
                    float hk = h0[k];
                    gi += hk * whh[d][j][k];
                    gf += hk * whh[d][13 + j][k];
                    gg += hk * whh[d][26 + j][k];
                    go += hk * whh[d][39 + j][k];
                }
            }
            float cc = sigf(gf) * c0[j] + sigf(gi) * tanh_(gg);
            float hh = sigf(go) * tanh_(cc);
            dec[(size_t)r * TWOH + d * H_ + j] = hh;
        }
    }
}

// ---------------------------------------------------------------------------
// K5: out[r][v] = dec[r][:] . Wout[v][:] + bout[v].
// 4 columns/thread (128 threads, VT=512): halves LDS-issue per FMA vs the
// 2-col version, float4 stores (1 KB/wave-inst). ~112 weight VGPRs/thread.
// ---------------------------------------------------------------------------
#define RT 64
#define VT 512
__global__ __launch_bounds__(128) void k_out(const float* __restrict__ dec,
        const float* __restrict__ Wout, const float* __restrict__ bout,
        float* __restrict__ out){
    __shared__ float dl[RT * 28];      // dec tile, rows padded to 28
    __shared__ float wl[VT * 26];      // Wout tile fp32 (53248 B)
    const int tid = threadIdx.x;
    const int r0 = blockIdx.x * RT;
    const int v0 = blockIdx.y * VT;
    const int nv = min(VT, V_ - v0);   // 512 or 320; both % 4 == 0

    for (int i = tid; i < RT * 28; i += 128){
        int rr = i / 28, k = i % 28;
        dl[i] = (k < TWOH) ? dec[(size_t)(r0 + rr) * TWOH + k] : 0.f;
    }
    {   // rows v0..v0+nv contiguous: nv*26 floats, nv*26 % 4 == 0
        const float4* src = (const float4*)(Wout + (size_t)v0 * TWOH);
        float4* dst4 = (float4*)wl;
        const int n4 = nv * TWOH / 4;
        for (int i = tid; i < n4; i += 128) dst4[i] = src[i];
    }
    __syncthreads();

    const int lv = 4 * tid;
    if (lv < nv){
        float w[4][28];
        #pragma unroll
        for (int c = 0; c < 4; ++c){
            #pragma unroll
            for (int k = 0; k < TWOH; ++k) w[c][k] = wl[(lv + c) * TWOH + k];
            w[c][26] = 0.f; w[c][27] = 0.f;
        }
        const int v = v0 + lv;
        const float b0 = bout[v],     b1 = bout[v + 1];
        const float b2 = bout[v + 2], b3 = bout[v + 3];
        float4* outp = (float4*)(out + (size_t)r0 * V_ + v);
        #pragma unroll 2
        for (int rr = 0; rr < RT; ++rr){
            float4 d4[7];
            const float4* dp4 = (const float4*)(dl + rr * 28);
            #pragma unroll
            for (int j = 0; j < 7; ++j) d4[j] = dp4[j];
            float s0 = b0, s1 = b1, s2 = b2, s3 = b3;
            const float* dk = (const float*)d4;
            #pragma unroll
            for (int k = 0; k < 28; ++k){
                float dv = dk[k];
                s0 += dv * w[0][k]; s1 += dv * w[1][k];
                s2 += dv * w[2][k]; s3 += dv * w[3][k];
            }
            outp[(size_t)rr * (V_ / 4)] = make_float4(s0, s1, s2, s3);
        }
    }
}

// ---------------------------------------------------------------------------
extern "C" void kernel_launch(void* const* d_in, const int* in_sizes, int n_in,
                              void* d_out, int out_size, void* d_ws, size_t ws_size,
                              hipStream_t stream){
    // ws layout (floats)
    int*   flag  = (int*)d_ws;
    float* cw    = (float*)d_ws + 64;          // converted weights: TOTW floats
    float* projF = cw + TOTW;                   // 8000*52
    float* projB = projF + 416000;
    float* state_h = projB + 416000;            // 128*26 each
    float* state_c = state_h + 3328;
    float* sh      = state_c + 3328;
    float* sc      = sh + 3328;
    float* dec     = sc + 3328;                 // 16384*26

    float* cEmb   = cw + 0;
    float* cWihF  = cw + 512064;
    float* cWhhF  = cw + 515392;
    float* cbF    = cw + 516068;
    float* cWihB  = cw + 516120;
    float* cWhhB  = cw + 519448;
    float* cbB    = cw + 520124;
    float* cWp1   = cw + 520176;
    float* cbp1   = cw + 520852;
    float* cWp2   = cw + 520878;
    float* cbp2   = cw + 521554;
    float* cghW1  = cw + 521580;
    float* cghb1  = cw + 521996;
    float* cghW2  = cw + 522012;
    float* cghb2  = cw + 522524;
    float* cghWf  = cw + 522556;
    float* cghbf  = cw + 523388;
    float* cgcW1  = cw + 523414;
    float* cgcb1  = cw + 523830;
    float* cgcW2  = cw + 523846;
    float* cgcb2  = cw + 524358;
    float* cgcWf  = cw + 524390;
    float* cgcbf  = cw + 525222;
    float* cWihFd = cw + 525248;
    float* cWhhFd = cw + 525300;
    float* cbFd   = cw + 525976;
    float* cWihBd = cw + 526028;
    float* cWhhBd = cw + 526080;
    float* cbBd   = cw + 526756;
    float* cWout  = cw + 526808;
    float* cbout  = cw + 734808;

    const int* x_tokens   = (const int*)d_in[0];
    const int* edge_index = (const int*)d_in[1];

    P31 a;
    for (int j = 0; j < 31; ++j) a.p[j] = d_in[2 + j];

    k_detect<<<1, 64, 0, stream>>>((const u16*)d_in[2], flag);
    k_convert<<<(TOTW + 255) / 256, 256, 0, stream>>>(a, flag, cw);
    k_proj<<<V_, 128, 0, stream>>>(cEmb, cWihF, cWihB, projF, projB);
    k_lstm<<<N_, 128, 0, stream>>>(x_tokens, projF, projB,
                                   cWhhF, cbF, cWhhB, cbB,
                                   cWp1, cbp1, cWp2, cbp2, state_h, state_c);
    k_gcn<<<2, 256, 0, stream>>>(edge_index, state_h, state_c,
                                 cghW1, cghb1, cghW2, cghb2, cghWf, cghbf,
                                 cgcW1, cgcb1, cgcW2, cgcb2, cgcWf, cgcbf,
                                 sh, sc);
    k_dec<<<(N_ * L_) / 256, 256, 0, stream>>>(x_tokens, sh, sc,
                                               cWihFd, cWhhFd, cbFd,
                                               cWihBd, cWhhBd, cbBd, dec);
    k_out<<<dim3((N_ * L_) / RT, (V_ + VT - 1) / VT), 128, 0, stream>>>(dec, cWout, cbout, (float*)d_out);
}

// Round 3
// 840.915 us; speedup vs baseline: 1.1313x; 1.0806x over previous
//
#include <hip/hip_runtime.h>
#include <stdint.h>

// Problem constants
#define N_    128
#define L_    128
#define V_    8000
#define IN_   64
#define H_    13
#define G_    52      // 4*H
#define E_    2048
#define TWOH  26
#define TOTW  742808  // total float elements across all 31 float inputs

typedef unsigned int   u32;
typedef unsigned short u16;

__device__ __forceinline__ float bfu(u16 u){
    u32 x = ((u32)u) << 16; float f; __builtin_memcpy(&f, &x, 4); return f;
}
// clamps are exact at saturation (sig(30)=1-9e-14, tanh(15)=1-2e-13)
__device__ __forceinline__ float sigf(float x){
    x = fminf(fmaxf(x, -30.f), 30.f);
    return 1.0f / (1.0f + __expf(-x));
}
__device__ __forceinline__ float tanh_(float x){
    x = fminf(fmaxf(x, -15.f), 15.f);
    float e = __expf(2.0f * x); return 1.0f - 2.0f / (e + 1.0f);
}

// ---------------------------------------------------------------------------
// K-1: dtype detection. fp32 arrays: low u16 of each dword is random mantissa
// bits -> bf16-exponent field uniform -> "wild". Genuine bf16 weights are
// essentially never wild. flag: 1 = fp32, 0 = bf16.
// ---------------------------------------------------------------------------
__global__ __launch_bounds__(64) void k_detect(const u16* __restrict__ emb_u16,
                                               int* __restrict__ flag){
    const int lane = threadIdx.x;
    int wild = 0;
    for (int i = lane; i < 1024; i += 64){
        u16 u = emb_u16[i];
        int e = (u >> 7) & 0xFF;
        int tame = (u == 0) || (u == 0x8000) || (e >= 0x60 && e <= 0x88);
        wild += !tame;
    }
    #pragma unroll
    for (int o = 32; o; o >>= 1) wild += __shfl_down(wild, o, 64);
    if (lane == 0) *flag = (wild > 200) ? 1 : 0;
}

// ---------------------------------------------------------------------------
// K0: materialize all 31 float inputs as fp32 into contiguous ws region.
// ---------------------------------------------------------------------------
struct P31 { const void* p[31]; };

__global__ __launch_bounds__(256) void k_convert(P31 a, const int* __restrict__ flag,
                                                 float* __restrict__ cw){
    const int fp32 = *flag;
    const int i = blockIdx.x * 256 + threadIdx.x;
    if (i >= TOTW) return;
    const int offs[32] = {
        0, 512064, 515392, 516068, 516120, 519448, 520124, 520176, 520852,
        520878, 521554, 521580, 521996, 522012, 522524, 522556, 523388,
        523414, 523830, 523846, 524358, 524390, 525222, 525248, 525300,
        525976, 526028, 526080, 526756, 526808, 734808, TOTW };
    int seg = 0;
    while (i >= offs[seg + 1]) ++seg;
    const int k = i - offs[seg];
    cw[i] = fp32 ? ((const float*)a.p[seg])[k] : bfu(((const u16*)a.p[seg])[k]);
}

// ---------------------------------------------------------------------------
// K1: proj[dir][t][g] = sum_k emb[t,k] * Wih_dir[g,k]
// v2: stage Wih in LDS (padded, conflict-free) amortized over TPER tokens
// per block -- kills the stride-256B uncoalesced global weight reads.
// ---------------------------------------------------------------------------
#define TPER 8
__global__ __launch_bounds__(256) void k_proj(const float* __restrict__ emb,
                                              const float* __restrict__ WihF,
                                              const float* __restrict__ WihB,
                                              float* __restrict__ projF,
                                              float* __restrict__ projB){
    __shared__ float w[2][G_][IN_ + 1];   // pad 65: bank (g+k)%32, conflict-free
    __shared__ float x[TPER][IN_];
    const int t0 = blockIdx.x * TPER;
    const int tid = threadIdx.x;
    for (int i = tid; i < 2 * G_ * IN_; i += 256){
        int d = i / (G_ * IN_), r = (i % (G_ * IN_)) / IN_, k = i % IN_;
        w[d][r][k] = (d ? WihB : WihF)[r * IN_ + k];
    }
    for (int i = tid; i < TPER * IN_; i += 256)
        x[i / IN_][i % IN_] = emb[(size_t)(t0 + i / IN_) * IN_ + i % IN_];
    __syncthreads();
    for (int i = tid; i < TPER * 2 * G_; i += 256){
        const int t = i / (2 * G_), rem = i % (2 * G_), d = rem / G_, g = rem % G_;
        float acc = 0.f;
        #pragma unroll
        for (int k = 0; k < IN_; ++k) acc += x[t][k] * w[d][g][k];
        (d ? projB : projF)[(size_t)(t0 + t) * G_ + g] = acc;
    }
}

// ---------------------------------------------------------------------------
// K2: biLSTM encoder. 1 block/node; wave0 = fwd, wave1 = bwd. Lane g (<52)
// owns one gate; h broadcast via shfl; next proj row prefetched.
// ---------------------------------------------------------------------------
__global__ __launch_bounds__(128) void k_lstm(const int* __restrict__ toks_g,
        const float* __restrict__ projF, const float* __restrict__ projB,
        const float* __restrict__ WhhF, const float* __restrict__ bF,
        const float* __restrict__ WhhB, const float* __restrict__ bB,
        const float* __restrict__ Wp1, const float* __restrict__ bp1,
        const float* __restrict__ Wp2, const float* __restrict__ bp2,
        float* __restrict__ state_h, float* __restrict__ state_c){
    __shared__ int   toks[L_];
    __shared__ float hcat[TWOH];
    __shared__ float ccat[TWOH];
    const int n = blockIdx.x, tid = threadIdx.x;
    const int wave = tid >> 6, lane = tid & 63;
    if (tid < L_) toks[tid] = toks_g[n * L_ + tid];

    const float* proj = wave ? projB : projF;
    const float* Whh  = wave ? WhhB : WhhF;
    const float* bp   = wave ? bB   : bF;

    float wh[H_];
    #pragma unroll
    for (int j = 0; j < H_; ++j) wh[j] = 0.f;
    float bb = 0.f;
    if (lane < G_){
        bb = bp[lane];
        #pragma unroll
        for (int j = 0; j < H_; ++j) wh[j] = Whh[lane * H_ + j];
    }
    __syncthreads();

    float h = 0.f, c = 0.f;
    int tok0 = wave ? toks[L_ - 1] : toks[0];
    float gpre = (lane < G_) ? proj[tok0 * G_ + lane] : 0.f;

    for (int t = 0; t < L_; ++t){
        float gv = gpre + bb;
        if (t + 1 < L_){
            int tn = wave ? toks[L_ - 2 - t] : toks[t + 1];
            gpre = (lane < G_) ? proj[tn * G_ + lane] : 0.f;   // prefetch
        }
        #pragma unroll
        for (int j = 0; j < H_; ++j) gv += __shfl(h, j, 64) * wh[j];
        float iv = __shfl(gv, lane,      64);
        float fv = __shfl(gv, lane + 13, 64);
        float gg = __shfl(gv, lane + 26, 64);
        float ov = __shfl(gv, lane + 39, 64);
        c = sigf(fv) * c + sigf(iv) * tanh_(gg);
        h = sigf(ov) * tanh_(c);
    }

    if (lane < H_){ hcat[wave * H_ + lane] = h; ccat[wave * H_ + lane] = c; }
    __syncthreads();

    if (lane < TWOH){
        if (wave == 0){
            float a = bp1[lane];
            #pragma unroll
            for (int k = 0; k < TWOH; ++k) a += hcat[k] * Wp1[lane * TWOH + k];
            state_h[n * TWOH + lane] = a;
        } else {
            float a = bp2[lane];
            #pragma unroll
            for (int k = 0; k < TWOH; ++k) a += ccat[k] * Wp2[lane * TWOH + k];
            state_c[n * TWOH + lane] = a;
        }
    }
}

// ---------------------------------------------------------------------------
// K3: two-layer GCN + final linear; one block per path (0 = h, 1 = c).
// GATHER formulation: build a dst-sorted CSR in LDS once, then each
// (node, feature) thread sums its in-edges. No feature atomics, no
// stride-32 same-bank serialization (xw padded to 33 floats/row).
// ---------------------------------------------------------------------------
__global__ __launch_bounds__(256) void k_gcn(const int* __restrict__ eidx,
        const float* __restrict__ state_h, const float* __restrict__ state_c,
        const float* gh_W1, const float* gh_b1, const float* gh_W2, const float* gh_b2,
        const float* gh_Wf, const float* gh_bf,
        const float* gc_W1, const float* gc_b1, const float* gc_W2, const float* gc_b2,
        const float* gc_Wf, const float* gc_bf,
        float* __restrict__ sh, float* __restrict__ sc){
    __shared__ float xs[N_][33];     // node features (padded: stride 33 banks)
    __shared__ float xw[N_][33];     // x @ W, gather source (padded)
    __shared__ float dinv[N_];
    __shared__ int   ptr[N_ + 1];    // CSR row offsets (by dst)
    __shared__ int   cnt[N_];
    __shared__ int   scn[N_];        // scan buffer
    __shared__ int   srcs[E_];       // CSR column (src node) array
    const int tid = threadIdx.x;
    const int p = blockIdx.x;
    const float* xin = p ? state_c : state_h;
    const float* W1  = p ? gc_W1 : gh_W1;  const float* b1  = p ? gc_b1 : gh_b1;
    const float* W2  = p ? gc_W2 : gh_W2;  const float* b2  = p ? gc_b2 : gh_b2;
    const float* Wf  = p ? gc_Wf : gh_Wf;  const float* bfp = p ? gc_bf : gh_bf;
    float* outp = p ? sc : sh;

    for (int i = tid; i < N_ * TWOH; i += 256) xs[i / TWOH][i % TWOH] = xin[i];
    if (tid < N_) cnt[tid] = 0;
    __syncthreads();
    // in-degree histogram (dst side); 2048 small LDS atomics, cheap
    for (int e = tid; e < E_; e += 256) atomicAdd(&cnt[eidx[E_ + e]], 1);
    __syncthreads();
    if (tid < N_){
        dinv[tid] = rsqrtf((float)cnt[tid] + 1.0f);   // +1 self loop
        scn[tid]  = cnt[tid];
    }
    __syncthreads();
    // Hillis-Steele inclusive scan over 128 entries (7 rounds)
    for (int off = 1; off < N_; off <<= 1){
        int v = 0;
        if (tid < N_ && tid >= off) v = scn[tid - off];
        __syncthreads();
        if (tid < N_) scn[tid] += v;
        __syncthreads();
    }
    if (tid < N_){
        ptr[tid + 1] = scn[tid];
        if (tid == 0) ptr[0] = 0;
        cnt[tid] = 0;
    }
    __syncthreads();
    // scatter edges into CSR slots (atomic slot grab per dst; order irrelevant)
    for (int e = tid; e < E_; e += 256){
        int d = eidx[E_ + e];
        int pos = atomicAdd(&cnt[d], 1);
        srcs[ptr[d] + pos] = eidx[e];
    }
    __syncthreads();

    // ---- layer 1: 26 -> 16 ----
    for (int i = tid; i < N_ * 16; i += 256){
        int nn = i >> 4, f = i & 15;
        float a = 0.f;
        #pragma unroll
        for (int k = 0; k < TWOH; ++k) a += xs[nn][k] * W1[k * 16 + f];
        xw[nn][f] = a;
    }
    __syncthreads();
    for (int i = tid; i < N_ * 16; i += 256){
        int nn = i >> 4, f = i & 15;
        float dn = dinv[nn];
        float a = dn * dn * xw[nn][f];                // self loop
        const int e1 = ptr[nn + 1];
        for (int e = ptr[nn]; e < e1; ++e){
            int s = srcs[e];
            a += dn * dinv[s] * xw[s][f];
        }
        a += b1[f];
        xs[nn][f] = a > 0.f ? a : 0.01f * a;          // xs reads all done
    }
    __syncthreads();

    // ---- layer 2: 16 -> 32 ----
    for (int i = tid; i < N_ * 32; i += 256){
        int nn = i >> 5, f = i & 31;
        float a = 0.f;
        #pragma unroll
        for (int k = 0; k < 16; ++k) a += xs[nn][k] * W2[k * 32 + f];
        xw[nn][f] = a;
    }
    __syncthreads();
    for (int i = tid; i < N_ * 32; i += 256){
        int nn = i >> 5, f = i & 31;
        float dn = dinv[nn];
        float a = dn * dn * xw[nn][f];
        const int e1 = ptr[nn + 1];
        for (int e = ptr[nn]; e < e1; ++e){
            int s = srcs[e];
            a += dn * dinv[s] * xw[s][f];
        }
        a += b2[f];
        xs[nn][f] = a > 0.f ? a : 0.01f * a;
    }
    __syncthreads();

    // ---- final linear: 32 -> 26 ----
    for (int i = tid; i < N_ * TWOH; i += 256){
        int nn = i / TWOH, d = i % TWOH;
        float a = bfp[d];
        #pragma unroll
        for (int k = 0; k < 32; ++k) a += xs[nn][k] * Wf[k * TWOH + d];
        outp[i] = a;
    }
}

// ---------------------------------------------------------------------------
// K4: decoder rows. One thread per (n,l). l>0: h0=c0=0 (scalar gates only).
// ---------------------------------------------------------------------------
__global__ __launch_bounds__(256) void k_dec(const int* __restrict__ toks,
        const float* __restrict__ sh, const float* __restrict__ sc,
        const float* WihF, const float* WhhF, const float* bF,
        const float* WihB, const float* WhhB, const float* bB,
        float* __restrict__ dec){
    __shared__ float wih[2][G_], bias[2][G_], whh[2][G_][H_];
    const int tid = threadIdx.x;
    for (int i = tid; i < 2 * G_; i += 256){
        int d = i / G_, k = i % G_;
        wih[d][k]  = (d ? WihB : WihF)[k];
        bias[d][k] = (d ? bB : bF)[k];
    }
    for (int i = tid; i < 2 * G_ * H_; i += 256){
        int d = i / (G_ * H_), rr = i % (G_ * H_), k = rr / H_, j = rr % H_;
        whh[d][k][j] = (d ? WhhB : WhhF)[k * H_ + j];
    }
    __syncthreads();

    const int r = blockIdx.x * 256 + tid;
    const int n = r >> 7, l = r & 127;
    const bool first = (l == 0);
    const float prev = first ? -1.0f : (float)toks[n * L_ + l - 1];

    for (int d = 0; d < 2; ++d){
        float h0[H_], c0[H_];
        #pragma unroll
        for (int j = 0; j < H_; ++j){
            h0[j] = first ? sh[n * TWOH + d * H_ + j] : 0.f;
            c0[j] = first ? sc[n * TWOH + d * H_ + j] : 0.f;
        }
        #pragma unroll
        for (int j = 0; j < H_; ++j){
            float gi = prev * wih[d][j]      + bias[d][j];
            float gf = prev * wih[d][13 + j] + bias[d][13 + j];
            float gg = prev * wih[d][26 + j] + bias[d][26 + j];
            float go = prev * wih[d][39 + j] + bias[d][39 + j];
            if (first){
                #pragma unroll
                for (int k = 0; k < H_; ++k){
                    float hk = h0[k];
                    gi += hk * whh[d][j][k];
                    gf += hk * whh[d][13 + j][k];
                    gg += hk * whh[d][26 + j][k];
                    go += hk * whh[d][39 + j][k];
                }
            }
            float cc = sigf(gf) * c0[j] + sigf(gi) * tanh_(gg);
            float hh = sigf(go) * tanh_(cc);
            dec[(size_t)r * TWOH + d * H_ + j] = hh;
        }
    }
}

// ---------------------------------------------------------------------------
// K5: out[r][v] = dec[r][:] . Wout[v][:] + bout[v].
// v3: VT=256, 256 threads, 1 col/thread. LDS 33.8 KB -> 4 blocks/CU x 4
// waves = 16 waves/CU (was 4): store latency actually hidden. dl reads are
// wave-uniform (broadcast). Two accumulators break the FMA chain.
// ---------------------------------------------------------------------------
#define RT 64
#define VT 256
__global__ __launch_bounds__(256) void k_out(const float* __restrict__ dec,
        const float* __restrict__ Wout, const float* __restrict__ bout,
        float* __restrict__ out){
    __shared__ float dl[RT * 28];      // dec tile, rows padded to 28 (7168 B)
    __shared__ float wl[VT * TWOH];    // Wout tile fp32 (26624 B)
    const int tid = threadIdx.x;
    const int r0 = blockIdx.x * RT;
    const int v0 = blockIdx.y * VT;
    const int nv = min(VT, V_ - v0);   // 256 or 64 (8000 = 31*256 + 64)

    for (int i = tid; i < RT * 28; i += 256){
        int rr = i / 28, k = i % 28;
        dl[i] = (k < TWOH) ? dec[(size_t)(r0 + rr) * TWOH + k] : 0.f;
    }
    {   // rows v0..v0+nv contiguous: nv*26 floats, nv*26 % 4 == 0
        const float4* src = (const float4*)(Wout + (size_t)v0 * TWOH);
        float4* dst4 = (float4*)wl;
        const int n4 = nv * TWOH / 4;
        for (int i = tid; i < n4; i += 256) dst4[i] = src[i];
    }
    __syncthreads();

    if (tid < nv){
        float w[28];
        #pragma unroll
        for (int k = 0; k < TWOH; ++k) w[k] = wl[tid * TWOH + k];
        w[26] = 0.f; w[27] = 0.f;
        const int v = v0 + tid;
        const float b0 = bout[v];
        float* outp = out + (size_t)r0 * V_ + v;
        for (int rr = 0; rr < RT; ++rr){
            float4 d4[7];
            const float4* dp4 = (const float4*)(dl + rr * 28);
            #pragma unroll
            for (int j = 0; j < 7; ++j) d4[j] = dp4[j];
            const float* dk = (const float*)d4;
            float sA = b0, sB = 0.f;
            #pragma unroll
            for (int k = 0; k < 28; k += 2){
                sA += dk[k]     * w[k];
                sB += dk[k + 1] * w[k + 1];
            }
            outp[(size_t)rr * V_] = sA + sB;
        }
    }
}

// ---------------------------------------------------------------------------
extern "C" void kernel_launch(void* const* d_in, const int* in_sizes, int n_in,
                              void* d_out, int out_size, void* d_ws, size_t ws_size,
                              hipStream_t stream){
    // ws layout (floats)
    int*   flag  = (int*)d_ws;
    float* cw    = (float*)d_ws + 64;          // converted weights: TOTW floats
    float* projF = cw + TOTW;                   // 8000*52
    float* projB = projF + 416000;
    float* state_h = projB + 416000;            // 128*26 each
    float* state_c = state_h + 3328;
    float* sh      = state_c + 3328;
    float* sc      = sh + 3328;
    float* dec     = sc + 3328;                 // 16384*26

    float* cEmb   = cw + 0;
    float* cWihF  = cw + 512064;
    float* cWhhF  = cw + 515392;
    float* cbF    = cw + 516068;
    float* cWihB  = cw + 516120;
    float* cWhhB  = cw + 519448;
    float* cbB    = cw + 520124;
    float* cWp1   = cw + 520176;
    float* cbp1   = cw + 520852;
    float* cWp2   = cw + 520878;
    float* cbp2   = cw + 521554;
    float* cghW1  = cw + 521580;
    float* cghb1  = cw + 521996;
    float* cghW2  = cw + 522012;
    float* cghb2  = cw + 522524;
    float* cghWf  = cw + 522556;
    float* cghbf  = cw + 523388;
    float* cgcW1  = cw + 523414;
    float* cgcb1  = cw + 523830;
    float* cgcW2  = cw + 523846;
    float* cgcb2  = cw + 524358;
    float* cgcWf  = cw + 524390;
    float* cgcbf  = cw + 525222;
    float* cWihFd = cw + 525248;
    float* cWhhFd = cw + 525300;
    float* cbFd   = cw + 525976;
    float* cWihBd = cw + 526028;
    float* cWhhBd = cw + 526080;
    float* cbBd   = cw + 526756;
    float* cWout  = cw + 526808;
    float* cbout  = cw + 734808;

    const int* x_tokens   = (const int*)d_in[0];
    const int* edge_index = (const int*)d_in[1];

    P31 a;
    for (int j = 0; j < 31; ++j) a.p[j] = d_in[2 + j];

    k_detect<<<1, 64, 0, stream>>>((const u16*)d_in[2], flag);
    k_convert<<<(TOTW + 255) / 256, 256, 0, stream>>>(a, flag, cw);
    k_proj<<<V_ / TPER, 256, 0, stream>>>(cEmb, cWihF, cWihB, projF, projB);
    k_lstm<<<N_, 128, 0, stream>>>(x_tokens, projF, projB,
                                   cWhhF, cbF, cWhhB, cbB,
                                   cWp1, cbp1, cWp2, cbp2, state_h, state_c);
    k_gcn<<<2, 256, 0, stream>>>(edge_index, state_h, state_c,
                                 cghW1, cghb1, cghW2, cghb2, cghWf, cghbf,
                                 cgcW1, cgcb1, cgcW2, cgcb2, cgcWf, cgcbf,
                                 sh, sc);
    k_dec<<<(N_ * L_) / 256, 256, 0, stream>>>(x_tokens, sh, sc,
                                               cWihFd, cWhhFd, cbFd,
                                               cWihBd, cWhhBd, cbBd, dec);
    k_out<<<dim3((N_ * L_) / RT, (V_ + VT - 1) / VT), 256, 0, stream>>>(dec, cWout, cbout, (float*)d_out);
}

// Round 4
// 797.599 us; speedup vs baseline: 1.1927x; 1.0543x over previous
//
#include <hip/hip_runtime.h>
#include <stdint.h>

// Problem constants
#define N_    128
#define L_    128
#define V_    8000
#define IN_   64
#define H_    13
#define G_    52      // 4*H
#define E_    2048
#define TWOH  26
#define TOTW  742808  // total float elements across all 31 float inputs

typedef unsigned int   u32;
typedef unsigned short u16;

__device__ __forceinline__ float bfu(u16 u){
    u32 x = ((u32)u) << 16; float f; __builtin_memcpy(&f, &x, 4); return f;
}
// clamps are exact at saturation (sig(30)=1-9e-14, tanh(15)=1-2e-13)
__device__ __forceinline__ float sigf(float x){
    x = fminf(fmaxf(x, -30.f), 30.f);
    return 1.0f / (1.0f + __expf(-x));
}
__device__ __forceinline__ float tanh_(float x){
    x = fminf(fmaxf(x, -15.f), 15.f);
    float e = __expf(2.0f * x); return 1.0f - 2.0f / (e + 1.0f);
}

// ---------------------------------------------------------------------------
// K-1: dtype detection. fp32 arrays: low u16 of each dword is random mantissa
// bits -> bf16-exponent field uniform -> "wild". Genuine bf16 weights are
// essentially never wild. flag: 1 = fp32, 0 = bf16.
// ---------------------------------------------------------------------------
__global__ __launch_bounds__(64) void k_detect(const u16* __restrict__ emb_u16,
                                               int* __restrict__ flag){
    const int lane = threadIdx.x;
    int wild = 0;
    for (int i = lane; i < 1024; i += 64){
        u16 u = emb_u16[i];
        int e = (u >> 7) & 0xFF;
        int tame = (u == 0) || (u == 0x8000) || (e >= 0x60 && e <= 0x88);
        wild += !tame;
    }
    #pragma unroll
    for (int o = 32; o; o >>= 1) wild += __shfl_down(wild, o, 64);
    if (lane == 0) *flag = (wild > 200) ? 1 : 0;
}

// ---------------------------------------------------------------------------
// K0: materialize all 31 float inputs as fp32 into contiguous ws region.
// v2: fast-path the 3 big segments (emb 69%, Wout 28%, bout) -- kills the
// up-to-31-iteration dependent .rodata search for 97% of threads.
// ---------------------------------------------------------------------------
struct P31 { const void* p[31]; };

__global__ __launch_bounds__(256) void k_convert(P31 a, const int* __restrict__ flag,
                                                 float* __restrict__ cw){
    const int fp32 = *flag;
    const int i = blockIdx.x * 256 + threadIdx.x;
    if (i >= TOTW) return;
    int seg, k;
    if (i < 512064){ seg = 0; k = i; }
    else if (i >= 734808){ seg = 30; k = i - 734808; }          // bout
    else if (i >= 526808){ seg = 29; k = i - 526808; }          // Wout
    else {
        const int offs[31] = {
            0, 512064, 515392, 516068, 516120, 519448, 520124, 520176, 520852,
            520878, 521554, 521580, 521996, 522012, 522524, 522556, 523388,
            523414, 523830, 523846, 524358, 524390, 525222, 525248, 525300,
            525976, 526028, 526080, 526756, 526808, 734808 };
        seg = 1;
        while (seg < 29 && i >= offs[seg + 1]) ++seg;
        k = i - offs[seg];
    }
    cw[i] = fp32 ? ((const float*)a.p[seg])[k] : bfu(((const u16*)a.p[seg])[k]);
}

// ---------------------------------------------------------------------------
// K1: proj[dir][t][g] = sum_k emb[t,k] * Wih_dir[g,k]
// v2: stage Wih in LDS (padded, conflict-free) amortized over TPER tokens
// per block -- kills the stride-256B uncoalesced global weight reads.
// ---------------------------------------------------------------------------
#define TPER 8
__global__ __launch_bounds__(256) void k_proj(const float* __restrict__ emb,
                                              const float* __restrict__ WihF,
                                              const float* __restrict__ WihB,
                                              float* __restrict__ projF,
                                              float* __restrict__ projB){
    __shared__ float w[2][G_][IN_ + 1];   // pad 65: bank (g+k)%32, conflict-free
    __shared__ float x[TPER][IN_];
    const int t0 = blockIdx.x * TPER;
    const int tid = threadIdx.x;
    for (int i = tid; i < 2 * G_ * IN_; i += 256){
        int d = i / (G_ * IN_), r = (i % (G_ * IN_)) / IN_, k = i % IN_;
        w[d][r][k] = (d ? WihB : WihF)[r * IN_ + k];
    }
    for (int i = tid; i < TPER * IN_; i += 256)
        x[i / IN_][i % IN_] = emb[(size_t)(t0 + i / IN_) * IN_ + i % IN_];
    __syncthreads();
    for (int i = tid; i < TPER * 2 * G_; i += 256){
        const int t = i / (2 * G_), rem = i % (2 * G_), d = rem / G_, g = rem % G_;
        float acc = 0.f;
        #pragma unroll
        for (int k = 0; k < IN_; ++k) acc += x[t][k] * w[d][g][k];
        (d ? projB : projF)[(size_t)(t0 + t) * G_ + g] = acc;
    }
}

// ---------------------------------------------------------------------------
// K2: biLSTM encoder. 1 block/node; wave0 = fwd, wave1 = bwd. Lane g (<52)
// owns one gate; h broadcast via shfl; next proj row prefetched.
// ---------------------------------------------------------------------------
__global__ __launch_bounds__(128) void k_lstm(const int* __restrict__ toks_g,
        const float* __restrict__ projF, const float* __restrict__ projB,
        const float* __restrict__ WhhF, const float* __restrict__ bF,
        const float* __restrict__ WhhB, const float* __restrict__ bB,
        const float* __restrict__ Wp1, const float* __restrict__ bp1,
        const float* __restrict__ Wp2, const float* __restrict__ bp2,
        float* __restrict__ state_h, float* __restrict__ state_c){
    __shared__ int   toks[L_];
    __shared__ float hcat[TWOH];
    __shared__ float ccat[TWOH];
    const int n = blockIdx.x, tid = threadIdx.x;
    const int wave = tid >> 6, lane = tid & 63;
    if (tid < L_) toks[tid] = toks_g[n * L_ + tid];

    const float* proj = wave ? projB : projF;
    const float* Whh  = wave ? WhhB : WhhF;
    const float* bp   = wave ? bB   : bF;

    float wh[H_];
    #pragma unroll
    for (int j = 0; j < H_; ++j) wh[j] = 0.f;
    float bb = 0.f;
    if (lane < G_){
        bb = bp[lane];
        #pragma unroll
        for (int j = 0; j < H_; ++j) wh[j] = Whh[lane * H_ + j];
    }
    __syncthreads();

    float h = 0.f, c = 0.f;
    int tok0 = wave ? toks[L_ - 1] : toks[0];
    float gpre = (lane < G_) ? proj[tok0 * G_ + lane] : 0.f;

    for (int t = 0; t < L_; ++t){
        float gv = gpre + bb;
        if (t + 1 < L_){
            int tn = wave ? toks[L_ - 2 - t] : toks[t + 1];
            gpre = (lane < G_) ? proj[tn * G_ + lane] : 0.f;   // prefetch
        }
        #pragma unroll
        for (int j = 0; j < H_; ++j) gv += __shfl(h, j, 64) * wh[j];
        float iv = __shfl(gv, lane,      64);
        float fv = __shfl(gv, lane + 13, 64);
        float gg = __shfl(gv, lane + 26, 64);
        float ov = __shfl(gv, lane + 39, 64);
        c = sigf(fv) * c + sigf(iv) * tanh_(gg);
        h = sigf(ov) * tanh_(c);
    }

    if (lane < H_){ hcat[wave * H_ + lane] = h; ccat[wave * H_ + lane] = c; }
    __syncthreads();

    if (lane < TWOH){
        if (wave == 0){
            float a = bp1[lane];
            #pragma unroll
            for (int k = 0; k < TWOH; ++k) a += hcat[k] * Wp1[lane * TWOH + k];
            state_h[n * TWOH + lane] = a;
        } else {
            float a = bp2[lane];
            #pragma unroll
            for (int k = 0; k < TWOH; ++k) a += ccat[k] * Wp2[lane * TWOH + k];
            state_c[n * TWOH + lane] = a;
        }
    }
}

// ---------------------------------------------------------------------------
// K3: two-layer GCN + final linear; one block per path (0 = h, 1 = c).
// GATHER formulation: build a dst-sorted CSR in LDS once, then each
// (node, feature) thread sums its in-edges. No feature atomics, no
// stride-32 same-bank serialization (xw padded to 33 floats/row).
// ---------------------------------------------------------------------------
__global__ __launch_bounds__(256) void k_gcn(const int* __restrict__ eidx,
        const float* __restrict__ state_h, const float* __restrict__ state_c,
        const float* gh_W1, const float* gh_b1, const float* gh_W2, const float* gh_b2,
        const float* gh_Wf, const float* gh_bf,
        const float* gc_W1, const float* gc_b1, const float* gc_W2, const float* gc_b2,
        const float* gc_Wf, const float* gc_bf,
        float* __restrict__ sh, float* __restrict__ sc){
    __shared__ float xs[N_][33];     // node features (padded: stride 33 banks)
    __shared__ float xw[N_][33];     // x @ W, gather source (padded)
    __shared__ float dinv[N_];
    __shared__ int   ptr[N_ + 1];    // CSR row offsets (by dst)
    __shared__ int   cnt[N_];
    __shared__ int   scn[N_];        // scan buffer
    __shared__ int   srcs[E_];       // CSR column (src node) array
    const int tid = threadIdx.x;
    const int p = blockIdx.x;
    const float* xin = p ? state_c : state_h;
    const float* W1  = p ? gc_W1 : gh_W1;  const float* b1  = p ? gc_b1 : gh_b1;
    const float* W2  = p ? gc_W2 : gh_W2;  const float* b2  = p ? gc_b2 : gh_b2;
    const float* Wf  = p ? gc_Wf : gh_Wf;  const float* bfp = p ? gc_bf : gh_bf;
    float* outp = p ? sc : sh;

    for (int i = tid; i < N_ * TWOH; i += 256) xs[i / TWOH][i % TWOH] = xin[i];
    if (tid < N_) cnt[tid] = 0;
    __syncthreads();
    // in-degree histogram (dst side); 2048 small LDS atomics, cheap
    for (int e = tid; e < E_; e += 256) atomicAdd(&cnt[eidx[E_ + e]], 1);
    __syncthreads();
    if (tid < N_){
        dinv[tid] = rsqrtf((float)cnt[tid] + 1.0f);   // +1 self loop
        scn[tid]  = cnt[tid];
    }
    __syncthreads();
    // Hillis-Steele inclusive scan over 128 entries (7 rounds)
    for (int off = 1; off < N_; off <<= 1){
        int v = 0;
        if (tid < N_ && tid >= off) v = scn[tid - off];
        __syncthreads();
        if (tid < N_) scn[tid] += v;
        __syncthreads();
    }
    if (tid < N_){
        ptr[tid + 1] = scn[tid];
        if (tid == 0) ptr[0] = 0;
        cnt[tid] = 0;
    }
    __syncthreads();
    // scatter edges into CSR slots (atomic slot grab per dst; order irrelevant)
    for (int e = tid; e < E_; e += 256){
        int d = eidx[E_ + e];
        int pos = atomicAdd(&cnt[d], 1);
        srcs[ptr[d] + pos] = eidx[e];
    }
    __syncthreads();

    // ---- layer 1: 26 -> 16 ----
    for (int i = tid; i < N_ * 16; i += 256){
        int nn = i >> 4, f = i & 15;
        float a = 0.f;
        #pragma unroll
        for (int k = 0; k < TWOH; ++k) a += xs[nn][k] * W1[k * 16 + f];
        xw[nn][f] = a;
    }
    __syncthreads();
    for (int i = tid; i < N_ * 16; i += 256){
        int nn = i >> 4, f = i & 15;
        float dn = dinv[nn];
        float a = dn * dn * xw[nn][f];                // self loop
        const int e1 = ptr[nn + 1];
        for (int e = ptr[nn]; e < e1; ++e){
            int s = srcs[e];
            a += dn * dinv[s] * xw[s][f];
        }
        a += b1[f];
        xs[nn][f] = a > 0.f ? a : 0.01f * a;          // xs reads all done
    }
    __syncthreads();

    // ---- layer 2: 16 -> 32 ----
    for (int i = tid; i < N_ * 32; i += 256){
        int nn = i >> 5, f = i & 31;
        float a = 0.f;
        #pragma unroll
        for (int k = 0; k < 16; ++k) a += xs[nn][k] * W2[k * 32 + f];
        xw[nn][f] = a;
    }
    __syncthreads();
    for (int i = tid; i < N_ * 32; i += 256){
        int nn = i >> 5, f = i & 31;
        float dn = dinv[nn];
        float a = dn * dn * xw[nn][f];
        const int e1 = ptr[nn + 1];
        for (int e = ptr[nn]; e < e1; ++e){
            int s = srcs[e];
            a += dn * dinv[s] * xw[s][f];
        }
        a += b2[f];
        xs[nn][f] = a > 0.f ? a : 0.01f * a;
    }
    __syncthreads();

    // ---- final linear: 32 -> 26 ----
    for (int i = tid; i < N_ * TWOH; i += 256){
        int nn = i / TWOH, d = i % TWOH;
        float a = bfp[d];
        #pragma unroll
        for (int k = 0; k < 32; ++k) a += xs[nn][k] * Wf[k * TWOH + d];
        outp[i] = a;
    }
}

// ---------------------------------------------------------------------------
// K4: decoder rows. One thread per (n,l). l>0: h0=c0=0 (scalar gates only).
// ---------------------------------------------------------------------------
__global__ __launch_bounds__(256) void k_dec(const int* __restrict__ toks,
        const float* __restrict__ sh, const float* __restrict__ sc,
        const float* WihF, const float* WhhF, const float* bF,
        const float* WihB, const float* WhhB, const float* bB,
        float* __restrict__ dec){
    __shared__ float wih[2][G_], bias[2][G_], whh[2][G_][H_];
    const int tid = threadIdx.x;
    for (int i = tid; i < 2 * G_; i += 256){
        int d = i / G_, k = i % G_;
        wih[d][k]  = (d ? WihB : WihF)[k];
        bias[d][k] = (d ? bB : bF)[k];
    }
    for (int i = tid; i < 2 * G_ * H_; i += 256){
        int d = i / (G_ * H_), rr = i % (G_ * H_), k = rr / H_, j = rr % H_;
        whh[d][k][j] = (d ? WhhB : WhhF)[k * H_ + j];
    }
    __syncthreads();

    const int r = blockIdx.x * 256 + tid;
    const int n = r >> 7, l = r & 127;
    const bool first = (l == 0);
    const float prev = first ? -1.0f : (float)toks[n * L_ + l - 1];

    for (int d = 0; d < 2; ++d){
        float h0[H_], c0[H_];
        #pragma unroll
        for (int j = 0; j < H_; ++j){
            h0[j] = first ? sh[n * TWOH + d * H_ + j] : 0.f;
            c0[j] = first ? sc[n * TWOH + d * H_ + j] : 0.f;
        }
        #pragma unroll
        for (int j = 0; j < H_; ++j){
            float gi = prev * wih[d][j]      + bias[d][j];
            float gf = prev * wih[d][13 + j] + bias[d][13 + j];
            float gg = prev * wih[d][26 + j] + bias[d][26 + j];
            float go = prev * wih[d][39 + j] + bias[d][39 + j];
            if (first){
                #pragma unroll
                for (int k = 0; k < H_; ++k){
                    float hk = h0[k];
                    gi += hk * whh[d][j][k];
                    gf += hk * whh[d][13 + j][k];
                    gg += hk * whh[d][26 + j][k];
                    go += hk * whh[d][39 + j][k];
                }
            }
            float cc = sigf(gf) * c0[j] + sigf(gi) * tanh_(gg);
            float hh = sigf(go) * tanh_(cc);
            dec[(size_t)r * TWOH + d * H_ + j] = hh;
        }
    }
}

// ---------------------------------------------------------------------------
// K5: out[r][v] = dec[r][:] . Wout[v][:] + bout[v].
// v4: dec rows read via WAVE-UNIFORM address (blockIdx + loop induction only)
// -> compiler scalarizes to s_load; zero LDS traffic for dec, no dl barrier.
// LDS = wl only (26.6 KB) -> 6 blocks/CU = 24 waves/CU. k_out should sit on
// its 83 us store floor with FMA (48 us) and scalar loads hidden beneath.
// ---------------------------------------------------------------------------
#define RT 64
#define VT 256
__global__ __launch_bounds__(256) void k_out(const float* __restrict__ dec,
        const float* __restrict__ Wout, const float* __restrict__ bout,
        float* __restrict__ out){
    __shared__ float wl[VT * TWOH];    // Wout tile fp32 (26624 B)
    const int tid = threadIdx.x;
    const int r0 = blockIdx.x * RT;
    const int v0 = blockIdx.y * VT;
    const int nv = min(VT, V_ - v0);   // 256 or 64 (8000 = 31*256 + 64)

    {   // rows v0..v0+nv contiguous: nv*26 floats, nv*26 % 4 == 0
        const float4* src = (const float4*)(Wout + (size_t)v0 * TWOH);
        float4* dst4 = (float4*)wl;
        const int n4 = nv * TWOH / 4;
        for (int i = tid; i < n4; i += 256) dst4[i] = src[i];
    }
    __syncthreads();

    if (tid < nv){
        float w[TWOH];
        #pragma unroll
        for (int k = 0; k < TWOH; ++k) w[k] = wl[tid * TWOH + k];
        const int v = v0 + tid;
        const float b0 = bout[v];
        float* outp = out + (size_t)r0 * V_ + v;
        const float* dp = dec + (size_t)r0 * TWOH;   // wave-uniform
        #pragma unroll 2
        for (int rr = 0; rr < RT; ++rr){
            float sA = b0, sB = 0.f;
            #pragma unroll
            for (int k = 0; k < TWOH; k += 2){
                sA += dp[k]     * w[k];
                sB += dp[k + 1] * w[k + 1];
            }
            outp[(size_t)rr * V_] = sA + sB;
            dp += TWOH;
        }
    }
}

// ---------------------------------------------------------------------------
extern "C" void kernel_launch(void* const* d_in, const int* in_sizes, int n_in,
                              void* d_out, int out_size, void* d_ws, size_t ws_size,
                              hipStream_t stream){
    // ws layout (floats)
    int*   flag  = (int*)d_ws;
    float* cw    = (float*)d_ws + 64;          // converted weights: TOTW floats
    float* projF = cw + TOTW;                   // 8000*52
    float* projB = projF + 416000;
    float* state_h = projB + 416000;            // 128*26 each
    float* state_c = state_h + 3328;
    float* sh      = state_c + 3328;
    float* sc      = sh + 3328;
    float* dec     = sc + 3328;                 // 16384*26

    float* cEmb   = cw + 0;
    float* cWihF  = cw + 512064;
    float* cWhhF  = cw + 515392;
    float* cbF    = cw + 516068;
    float* cWihB  = cw + 516120;
    float* cWhhB  = cw + 519448;
    float* cbB    = cw + 520124;
    float* cWp1   = cw + 520176;
    float* cbp1   = cw + 520852;
    float* cWp2   = cw + 520878;
    float* cbp2   = cw + 521554;
    float* cghW1  = cw + 521580;
    float* cghb1  = cw + 521996;
    float* cghW2  = cw + 522012;
    float* cghb2  = cw + 522524;
    float* cghWf  = cw + 522556;
    float* cghbf  = cw + 523388;
    float* cgcW1  = cw + 523414;
    float* cgcb1  = cw + 523830;
    float* cgcW2  = cw + 523846;
    float* cgcb2  = cw + 524358;
    float* cgcWf  = cw + 524390;
    float* cgcbf  = cw + 525222;
    float* cWihFd = cw + 525248;
    float* cWhhFd = cw + 525300;
    float* cbFd   = cw + 525976;
    float* cWihBd = cw + 526028;
    float* cWhhBd = cw + 526080;
    float* cbBd   = cw + 526756;
    float* cWout  = cw + 526808;
    float* cbout  = cw + 734808;

    const int* x_tokens   = (const int*)d_in[0];
    const int* edge_index = (const int*)d_in[1];

    P31 a;
    for (int j = 0; j < 31; ++j) a.p[j] = d_in[2 + j];

    k_detect<<<1, 64, 0, stream>>>((const u16*)d_in[2], flag);
    k_convert<<<(TOTW + 255) / 256, 256, 0, stream>>>(a, flag, cw);
    k_proj<<<V_ / TPER, 256, 0, stream>>>(cEmb, cWihF, cWihB, projF, projB);
    k_lstm<<<N_, 128, 0, stream>>>(x_tokens, projF, projB,
                                   cWhhF, cbF, cWhhB, cbB,
                                   cWp1, cbp1, cWp2, cbp2, state_h, state_c);
    k_gcn<<<2, 256, 0, stream>>>(edge_index, state_h, state_c,
                                 cghW1, cghb1, cghW2, cghb2, cghWf, cghbf,
                                 cgcW1, cgcb1, cgcW2, cgcb2, cgcWf, cgcbf,
                                 sh, sc);
    k_dec<<<(N_ * L_) / 256, 256, 0, stream>>>(x_tokens, sh, sc,
                                               cWihFd, cWhhFd, cbFd,
                                               cWihBd, cWhhBd, cbBd, dec);
    k_out<<<dim3((N_ * L_) / RT, (V_ + VT - 1) / VT), 256, 0, stream>>>(dec, cWout, cbout, (float*)d_out);
}